// Round 6
// baseline (202.310 us; speedup 1.0000x reference)
//
#include <hip/hip_runtime.h>
#include <hip/hip_bf16.h>
#include <math.h>

#define D 1024
#define H 16
#define DH 64
#define L 2048
#define B 2
#define NROW (B * L)  // 4096
#define EPS 1e-5f

typedef _Float16 half8 __attribute__((ext_vector_type(8)));
typedef _Float16 half4v __attribute__((ext_vector_type(4)));
typedef float f32x4 __attribute__((ext_vector_type(4)));

// ---------------------------------------------------------------------------
// K1: prep kernel — fuses 4 independent preprocessing jobs, block-ranged:
//  [0,4096)      LN1 (stats+apply) -> h16
//  [4096,6144)   f32->f16 weight convert (w_qkv then out_w)
//  [6144,6160)   segment bounds from sorted seq_id
//  [6160,6416)   rope cos/sin table [L][32] (float2)
// ---------------------------------------------------------------------------
__global__ __launch_bounds__(256) void prep_kernel(const float* __restrict__ x,
                                                   const float* __restrict__ lw,
                                                   const float* __restrict__ lb,
                                                   _Float16* __restrict__ h16,
                                                   const float* __restrict__ wqkv,
                                                   _Float16* __restrict__ wqkv16,
                                                   const float* __restrict__ outw,
                                                   _Float16* __restrict__ outw16,
                                                   const int* __restrict__ seq_id,
                                                   int* __restrict__ lo,
                                                   int* __restrict__ hi,
                                                   float2* __restrict__ rtab) {
    int blk = blockIdx.x;
    int t = threadIdx.x;
    if (blk < 4096) {
        // ---- LN1 row ----
        int r = blk;
        const float* xr = x + (size_t)r * D;
        float4 v = *(const float4*)&xr[t * 4];
        float s = v.x + v.y + v.z + v.w;
        float sq = v.x * v.x + v.y * v.y + v.z * v.z + v.w * v.w;
        for (int off = 32; off > 0; off >>= 1) {
            s += __shfl_xor(s, off, 64);
            sq += __shfl_xor(sq, off, 64);
        }
        __shared__ float ls[4], lq[4];
        int wave = t >> 6;
        if ((t & 63) == 0) { ls[wave] = s; lq[wave] = sq; }
        __syncthreads();
        float S = ls[0] + ls[1] + ls[2] + ls[3];
        float Q = lq[0] + lq[1] + lq[2] + lq[3];
        float mu = S / (float)D;
        float rs = rsqrtf(Q / (float)D - mu * mu + EPS);
        float4 w4 = *(const float4*)&lw[t * 4];
        float4 b4 = *(const float4*)&lb[t * 4];
        half4v o = {(_Float16)((v.x - mu) * rs * w4.x + b4.x),
                    (_Float16)((v.y - mu) * rs * w4.y + b4.y),
                    (_Float16)((v.z - mu) * rs * w4.z + b4.z),
                    (_Float16)((v.w - mu) * rs * w4.w + b4.w)};
        *(half4v*)&h16[(size_t)r * D + t * 4] = o;
    } else if (blk < 6144) {
        // ---- weight convert ----
        int base = blk - 4096;
        const float* src;
        _Float16* dst;
        if (base < 1536) { src = wqkv; dst = wqkv16; }
        else             { src = outw; dst = outw16; base -= 1536; }
        int i = (base * 256 + t) * 8;
        float4 a = *(const float4*)&src[i];
        float4 b = *(const float4*)&src[i + 4];
        half8 h = {(_Float16)a.x, (_Float16)a.y, (_Float16)a.z, (_Float16)a.w,
                   (_Float16)b.x, (_Float16)b.y, (_Float16)b.z, (_Float16)b.w};
        *(half8*)&dst[i] = h;
    } else if (blk < 6160) {
        // ---- segment bounds ----
        int idx = (blk - 6144) * 256 + t;
        int b = idx / L, l = idx - b * L;
        const int* row = seq_id + (size_t)b * L;
        int v = row[l];
        int a = 0, c = L;
        while (a < c) { int m = (a + c) >> 1; if (row[m] < v) a = m + 1; else c = m; }
        lo[idx] = a;
        a = 0; c = L;
        while (a < c) { int m = (a + c) >> 1; if (row[m] <= v) a = m + 1; else c = m; }
        hi[idx] = a;
    } else {
        // ---- rope table: rtab[l*32+fi] = (cos, sin) of l * 10000^(-fi/32) ----
        int idx = (blk - 6160) * 256 + t;  // 0..65535
        int l = idx >> 5, fi = idx & 31;
        float invf = expf(-(float)fi * 0.28782313662425572f);  // ln(10000)/32
        float sn, cs;
        sincosf((float)l * invf, &sn, &cs);
        rtab[idx] = make_float2(cs, sn);
    }
}

// ---------------------------------------------------------------------------
// K2: f16 MFMA GEMM  C[M,N] = A[M,1024] * W[N,1024]^T
// BM x BN tile, BK=32 (16 KB LDS -> high occupancy), 4 waves in 2x2.
// global_load_lds width=16; XOR source-swizzle: lane e stages global chunk
// (e&3)^((row>>1)&3) into LDS slot e; fragment read slot quad^((col>>1)&3)
// -> bank group (col&1)*4 + (quad^((col>>1)&3)): all 8 groups, 2-way = free.
// ---------------------------------------------------------------------------
template <typename OutT, int BM, int BN>
__global__ __launch_bounds__(256) void gemm_f16_kernel(const _Float16* __restrict__ A,
                                                       const _Float16* __restrict__ W,
                                                       OutT* __restrict__ C, int N) {
    constexpr int WM = BM / 2, WN = BN / 2;
    constexpr int MT = WM / 16, NT = WN / 16;
    __shared__ _Float16 As[BM * 32];
    __shared__ _Float16 Bs[BN * 32];
    int t = threadIdx.x;
    int w = t >> 6, lane = t & 63;
    int quad = lane >> 4, col = lane & 15;
    int m0 = blockIdx.y * BM, n0 = blockIdx.x * BN;
    int mw = (w >> 1) * WM, nw = (w & 1) * WN;
    int sw = (col >> 1) & 3;  // fragment-read swizzle == (row>>1)&3 for row=…+col

    f32x4 acc[MT][NT] = {};

    for (int k0 = 0; k0 < 1024; k0 += 32) {
#pragma unroll
        for (int i = 0; i < BM / 64; i++) {
            int e = t + i * 256;
            int row = e >> 2, kc = (e & 3) ^ ((row >> 1) & 3);
            __builtin_amdgcn_global_load_lds(
                (const __attribute__((address_space(1))) void*)&A[(size_t)(m0 + row) * 1024 + k0 + kc * 8],
                (__attribute__((address_space(3))) void*)&As[e * 8], 16, 0, 0);
        }
#pragma unroll
        for (int i = 0; i < BN / 64; i++) {
            int e = t + i * 256;
            int row = e >> 2, kc = (e & 3) ^ ((row >> 1) & 3);
            __builtin_amdgcn_global_load_lds(
                (const __attribute__((address_space(1))) void*)&W[(size_t)(n0 + row) * 1024 + k0 + kc * 8],
                (__attribute__((address_space(3))) void*)&Bs[e * 8], 16, 0, 0);
        }
        __syncthreads();
        half8 af[MT], bf[NT];
#pragma unroll
        for (int mt = 0; mt < MT; mt++)
            af[mt] = *(const half8*)&As[(mw + mt * 16 + col) * 32 + ((quad ^ sw) << 3)];
#pragma unroll
        for (int nt = 0; nt < NT; nt++)
            bf[nt] = *(const half8*)&Bs[(nw + nt * 16 + col) * 32 + ((quad ^ sw) << 3)];
#pragma unroll
        for (int mt = 0; mt < MT; mt++)
#pragma unroll
            for (int nt = 0; nt < NT; nt++)
                acc[mt][nt] = __builtin_amdgcn_mfma_f32_16x16x32_f16(af[mt], bf[nt], acc[mt][nt], 0, 0, 0);
        __syncthreads();
    }

#pragma unroll
    for (int mt = 0; mt < MT; mt++)
#pragma unroll
        for (int nt = 0; nt < NT; nt++)
#pragma unroll
            for (int r = 0; r < 4; r++) {
                int row = m0 + mw + mt * 16 + quad * 4 + r;
                int cc = n0 + nw + nt * 16 + col;
                C[(size_t)row * N + cc] = (OutT)acc[mt][nt][r];
            }
}

// ---------------------------------------------------------------------------
// K3: mid kernel — fuses:
//  [0,8192)      Q/K LayerNorm + RoPE (table-based) -> f16 q_r/k_r [B,H,L,DH]
//  [8192,9216)   V extract/transpose -> f16 v_t [B*H][DH][L]
// ---------------------------------------------------------------------------
__global__ __launch_bounds__(256) void mid_kernel(const _Float16* __restrict__ qkv,
                                                  const float* __restrict__ qw,
                                                  const float* __restrict__ kw,
                                                  const float2* __restrict__ rtab,
                                                  _Float16* __restrict__ q_r,
                                                  _Float16* __restrict__ k_r,
                                                  _Float16* __restrict__ v_t) {
    __shared__ float ls[4], lq[4];
    __shared__ _Float16 T[64][72];
    int blk = blockIdx.x;
    int t = threadIdx.x;
    if (blk < 8192) {
        int r = blk >> 1;
        int which = blk & 1;  // 0 = q, 1 = k
        const _Float16* src = qkv + (size_t)r * 3072 + which * 1024;
        const float* w = which ? kw : qw;
        _Float16* dst = which ? k_r : q_r;

        float vals[4];
        float s = 0.f, sq = 0.f;
#pragma unroll
        for (int i = 0; i < 4; i++) {
            float v = (float)src[t + i * 256];
            vals[i] = v;
            s += v;
            sq += v * v;
        }
        for (int off = 32; off > 0; off >>= 1) {
            s += __shfl_xor(s, off, 64);
            sq += __shfl_xor(sq, off, 64);
        }
        int wave = t >> 6;
        if ((t & 63) == 0) { ls[wave] = s; lq[wave] = sq; }
        __syncthreads();
        float S = ls[0] + ls[1] + ls[2] + ls[3];
        float Q = lq[0] + lq[1] + lq[2] + lq[3];
        float mu = S / 1024.f;
        float rs = rsqrtf(Q / 1024.f - mu * mu + EPS);

        int l = r & (L - 1);
        int b = r >> 11;
#pragma unroll
        for (int i = 0; i < 4; i++) {
            int j = t + i * 256;
            float y = (vals[i] - mu) * rs * w[j];
            float p = __shfl_xor(y, 32, 64);  // partner element j^32 (same head)
            int dh = j & 63, hh = j >> 6;
            float2 cs = rtab[l * 32 + (dh & 31)];
            float out = (dh < 32) ? (y * cs.x - p * cs.y) : (y * cs.x + p * cs.y);
            dst[((size_t)((b * H + hh) * L + l)) * 64 + dh] = (_Float16)out;
        }
    } else {
        int vb = blk - 8192;
        int bh = vb >> 5;
        int b = bh >> 4, h = bh & 15;
        int l0 = (vb & 31) * 64;
#pragma unroll
        for (int i = 0; i < 2; i++) {
            int e = t + i * 256;
            int li = e >> 3, ch = e & 7;
            half8 hv = *(const half8*)&qkv[((size_t)(b * L + l0 + li)) * 3072 + 2048 + h * 64 + ch * 8];
            *(half8*)&T[li][ch * 8] = hv;
        }
        __syncthreads();
#pragma unroll
        for (int i = 0; i < 2; i++) {
            int e = t + i * 256;
            int d = e >> 3, ch = e & 7;
            half8 hv;
#pragma unroll
            for (int j = 0; j < 8; j++) hv[j] = T[ch * 8 + j][d];
            *(half8*)&v_t[((size_t)(bh * 64 + d)) * 2048 + l0 + ch * 8] = hv;
        }
    }
}

// ---------------------------------------------------------------------------
// K4: MFMA flash attention, segment-pruned. ctx output in f16.
// ---------------------------------------------------------------------------
__global__ __launch_bounds__(256) void attn_mfma_kernel(const _Float16* __restrict__ q_r,
                                                        const _Float16* __restrict__ k_r,
                                                        const _Float16* __restrict__ v_t,
                                                        const int* __restrict__ lo_arr,
                                                        const int* __restrict__ hi_arr,
                                                        _Float16* __restrict__ ctx) {
    __shared__ _Float16 Ks[64][72];
    __shared__ _Float16 VsT[64][72];
    __shared__ _Float16 Ps[4][16][72];
    int bh = blockIdx.y;
    int b = bh >> 4, h = bh & 15;
    int l0 = blockIdx.x * 64;
    int t = threadIdx.x;
    int w = t >> 6, lane = t & 63;
    int quad = lane >> 4, col = lane & 15;
    int rbase = l0 + w * 16;

    half8 qf0, qf1;
    {
        const _Float16* qp = q_r + ((size_t)(bh * L + rbase + col)) * 64 + quad * 8;
        qf0 = *(const half8*)qp;
        qf1 = *(const half8*)(qp + 32);
    }
    int myrow = rbase + quad * 4;
    int lo_r[4], hi_r[4];
#pragma unroll
    for (int r = 0; r < 4; r++) {
        lo_r[r] = lo_arr[b * L + myrow + r];
        hi_r[r] = hi_arr[b * L + myrow + r];
    }

    f32x4 o[4] = {{0.f, 0.f, 0.f, 0.f}, {0.f, 0.f, 0.f, 0.f},
                  {0.f, 0.f, 0.f, 0.f}, {0.f, 0.f, 0.f, 0.f}};
    float m_run[4], l_run[4];
#pragma unroll
    for (int r = 0; r < 4; r++) { m_run[r] = -1e30f; l_run[r] = 0.f; }

    int blo = lo_arr[b * L + l0] & ~63;
    int bhi = hi_arr[b * L + l0 + 63];

    for (int m0 = blo; m0 < bhi; m0 += 64) {
#pragma unroll
        for (int i = 0; i < 2; i++) {
            int e = t + i * 256;
            int row = e >> 3, ch = e & 7;
            *(uint4*)&Ks[row][ch * 8] =
                *(const uint4*)&k_r[((size_t)(bh * L + m0 + row)) * 64 + ch * 8];
            *(uint4*)&VsT[row][ch * 8] =
                *(const uint4*)&v_t[((size_t)(bh * 64 + row)) * 2048 + m0 + ch * 8];
        }
        __syncthreads();

        f32x4 s[4] = {{0.f, 0.f, 0.f, 0.f}, {0.f, 0.f, 0.f, 0.f},
                      {0.f, 0.f, 0.f, 0.f}, {0.f, 0.f, 0.f, 0.f}};
#pragma unroll
        for (int nt = 0; nt < 4; nt++) {
            const _Float16* kp = &Ks[nt * 16 + col][quad * 8];
            half8 kf0 = *(const half8*)kp;
            half8 kf1 = *(const half8*)(kp + 32);
            s[nt] = __builtin_amdgcn_mfma_f32_16x16x32_f16(qf0, kf0, s[nt], 0, 0, 0);
            s[nt] = __builtin_amdgcn_mfma_f32_16x16x32_f16(qf1, kf1, s[nt], 0, 0, 0);
        }

        float p[4][4];
#pragma unroll
        for (int nt = 0; nt < 4; nt++) {
            int key = m0 + nt * 16 + col;
#pragma unroll
            for (int r = 0; r < 4; r++) {
                float v = s[nt][r] * 0.125f;
                p[nt][r] = (key >= lo_r[r] && key < hi_r[r]) ? v : -INFINITY;
            }
        }

        float corr[4];
#pragma unroll
        for (int r = 0; r < 4; r++) {
            float rm = fmaxf(fmaxf(p[0][r], p[1][r]), fmaxf(p[2][r], p[3][r]));
#pragma unroll
            for (int off = 1; off < 16; off <<= 1) rm = fmaxf(rm, __shfl_xor(rm, off, 64));
            float nm = fmaxf(m_run[r], rm);
            corr[r] = __expf(m_run[r] - nm);
            m_run[r] = nm;
            float rs = 0.f;
#pragma unroll
            for (int nt = 0; nt < 4; nt++) {
                float e = __expf(p[nt][r] - nm);
                p[nt][r] = e;
                rs += e;
            }
#pragma unroll
            for (int off = 1; off < 16; off <<= 1) rs += __shfl_xor(rs, off, 64);
            l_run[r] = l_run[r] * corr[r] + rs;
        }

#pragma unroll
        for (int nt = 0; nt < 4; nt++)
#pragma unroll
            for (int r = 0; r < 4; r++) {
                o[nt][r] *= corr[r];
                Ps[w][quad * 4 + r][nt * 16 + col] = (_Float16)p[nt][r];
            }
        __syncthreads();

        half8 pf0 = *(const half8*)&Ps[w][col][quad * 8];
        half8 pf1 = *(const half8*)&Ps[w][col][32 + quad * 8];
#pragma unroll
        for (int nt = 0; nt < 4; nt++) {
            const _Float16* vp = &VsT[nt * 16 + col][quad * 8];
            half8 vf0 = *(const half8*)vp;
            half8 vf1 = *(const half8*)(vp + 32);
            o[nt] = __builtin_amdgcn_mfma_f32_16x16x32_f16(pf0, vf0, o[nt], 0, 0, 0);
            o[nt] = __builtin_amdgcn_mfma_f32_16x16x32_f16(pf1, vf1, o[nt], 0, 0, 0);
        }
        __syncthreads();
    }

#pragma unroll
    for (int nt = 0; nt < 4; nt++)
#pragma unroll
        for (int r = 0; r < 4; r++) {
            int row = myrow + r;
            ctx[((size_t)(b * L + row)) * 1024 + h * 64 + nt * 16 + col] =
                (_Float16)(o[nt][r] / l_run[r]);
        }
}

// ---------------------------------------------------------------------------
// launch
// ---------------------------------------------------------------------------
extern "C" void kernel_launch(void* const* d_in, const int* in_sizes, int n_in,
                              void* d_out, int out_size, void* d_ws, size_t ws_size,
                              hipStream_t stream) {
    const float* x      = (const float*)d_in[0];
    const int*   seq_id = (const int*)d_in[1];
    const float* ln1_w  = (const float*)d_in[2];
    const float* ln1_b  = (const float*)d_in[3];
    const float* w_qkv  = (const float*)d_in[4];
    const float* q_ln_w = (const float*)d_in[5];
    const float* k_ln_w = (const float*)d_in[6];
    const float* out_w  = (const float*)d_in[7];
    float* out = (float*)d_out;

    char* ws = (char*)d_ws;
    int*      lo     = (int*)(ws);                        // 16 KB
    int*      hi     = (int*)(ws + (64 << 10));           // 16 KB
    float2*   rtab   = (float2*)(ws + (128 << 10));       // [2048][32] f32x2, 512 KB
    _Float16* h16    = (_Float16*)(ws + (1ull << 20));    // [4096,1024] 8 MB
    _Float16* wqkv16 = (_Float16*)(ws + (10ull << 20));   // [3072,1024] 6 MB
    _Float16* outw16 = (_Float16*)(ws + (17ull << 20));   // [1024,1024] 2 MB
    _Float16* qkv16  = (_Float16*)(ws + (20ull << 20));   // [4096,3072] 24 MB
    _Float16* q_r    = (_Float16*)(ws + (45ull << 20));   // [B,H,L,DH] 8 MB
    _Float16* k_r    = (_Float16*)(ws + (54ull << 20));   // 8 MB
    _Float16* v_t    = (_Float16*)(ws + (63ull << 20));   // [B,H,DH,L] 8 MB
    _Float16* ctx16  = (_Float16*)(ws + (72ull << 20));   // [4096,1024] 8 MB

    prep_kernel<<<dim3(6416), dim3(256), 0, stream>>>(
        x, ln1_w, ln1_b, h16, w_qkv, wqkv16, out_w, outw16, seq_id, lo, hi, rtab);
    gemm_f16_kernel<_Float16, 128, 128><<<dim3(3072 / 128, NROW / 128), dim3(256), 0, stream>>>(
        h16, wqkv16, qkv16, 3072);
    mid_kernel<<<dim3(9216), dim3(256), 0, stream>>>(qkv16, q_ln_w, k_ln_w, rtab, q_r, k_r, v_t);
    attn_mfma_kernel<<<dim3(L / 64, B * H), dim3(256), 0, stream>>>(q_r, k_r, v_t, lo, hi, ctx16);
    gemm_f16_kernel<float, 128, 64><<<dim3(1024 / 64, NROW / 128), dim3(256), 0, stream>>>(
        ctx16, outw16, out, 1024);

    (void)in_sizes; (void)n_in; (void)out_size; (void)ws_size;
}

// Round 7
// 198.689 us; speedup vs baseline: 1.0182x; 1.0182x over previous
//
#include <hip/hip_runtime.h>
#include <hip/hip_bf16.h>
#include <math.h>

#define D 1024
#define H 16
#define DH 64
#define L 2048
#define B 2
#define NROW (B * L)  // 4096
#define EPS 1e-5f

typedef _Float16 half8 __attribute__((ext_vector_type(8)));
typedef _Float16 half4v __attribute__((ext_vector_type(4)));
typedef float f32x4 __attribute__((ext_vector_type(4)));

// ---------------------------------------------------------------------------
// K1: prep kernel — fuses 4 independent preprocessing jobs, block-ranged:
//  [0,4096)      LN1 (stats+apply) -> h16
//  [4096,6144)   f32->f16 weight convert (w_qkv then out_w)
//  [6144,6160)   segment bounds from sorted seq_id
//  [6160,6416)   rope cos/sin table [L][32] (float2)
// ---------------------------------------------------------------------------
__global__ __launch_bounds__(256) void prep_kernel(const float* __restrict__ x,
                                                   const float* __restrict__ lw,
                                                   const float* __restrict__ lb,
                                                   _Float16* __restrict__ h16,
                                                   const float* __restrict__ wqkv,
                                                   _Float16* __restrict__ wqkv16,
                                                   const float* __restrict__ outw,
                                                   _Float16* __restrict__ outw16,
                                                   const int* __restrict__ seq_id,
                                                   int* __restrict__ lo,
                                                   int* __restrict__ hi,
                                                   float2* __restrict__ rtab) {
    int blk = blockIdx.x;
    int t = threadIdx.x;
    if (blk < 4096) {
        // ---- LN1 row ----
        int r = blk;
        const float* xr = x + (size_t)r * D;
        float4 v = *(const float4*)&xr[t * 4];
        float s = v.x + v.y + v.z + v.w;
        float sq = v.x * v.x + v.y * v.y + v.z * v.z + v.w * v.w;
        for (int off = 32; off > 0; off >>= 1) {
            s += __shfl_xor(s, off, 64);
            sq += __shfl_xor(sq, off, 64);
        }
        __shared__ float ls[4], lq[4];
        int wave = t >> 6;
        if ((t & 63) == 0) { ls[wave] = s; lq[wave] = sq; }
        __syncthreads();
        float S = ls[0] + ls[1] + ls[2] + ls[3];
        float Q = lq[0] + lq[1] + lq[2] + lq[3];
        float mu = S / (float)D;
        float rs = rsqrtf(Q / (float)D - mu * mu + EPS);
        float4 w4 = *(const float4*)&lw[t * 4];
        float4 b4 = *(const float4*)&lb[t * 4];
        half4v o = {(_Float16)((v.x - mu) * rs * w4.x + b4.x),
                    (_Float16)((v.y - mu) * rs * w4.y + b4.y),
                    (_Float16)((v.z - mu) * rs * w4.z + b4.z),
                    (_Float16)((v.w - mu) * rs * w4.w + b4.w)};
        *(half4v*)&h16[(size_t)r * D + t * 4] = o;
    } else if (blk < 6144) {
        // ---- weight convert ----
        int base = blk - 4096;
        const float* src;
        _Float16* dst;
        if (base < 1536) { src = wqkv; dst = wqkv16; }
        else             { src = outw; dst = outw16; base -= 1536; }
        int i = (base * 256 + t) * 8;
        float4 a = *(const float4*)&src[i];
        float4 b = *(const float4*)&src[i + 4];
        half8 h = {(_Float16)a.x, (_Float16)a.y, (_Float16)a.z, (_Float16)a.w,
                   (_Float16)b.x, (_Float16)b.y, (_Float16)b.z, (_Float16)b.w};
        *(half8*)&dst[i] = h;
    } else if (blk < 6160) {
        // ---- segment bounds ----
        int idx = (blk - 6144) * 256 + t;
        int b = idx / L, l = idx - b * L;
        const int* row = seq_id + (size_t)b * L;
        int v = row[l];
        int a = 0, c = L;
        while (a < c) { int m = (a + c) >> 1; if (row[m] < v) a = m + 1; else c = m; }
        lo[idx] = a;
        a = 0; c = L;
        while (a < c) { int m = (a + c) >> 1; if (row[m] <= v) a = m + 1; else c = m; }
        hi[idx] = a;
    } else {
        // ---- rope table: rtab[l*32+fi] = (cos, sin) of l * 10000^(-fi/32) ----
        int idx = (blk - 6160) * 256 + t;  // 0..65535
        int l = idx >> 5, fi = idx & 31;
        float invf = expf(-(float)fi * 0.28782313662425572f);  // ln(10000)/32
        float sn, cs;
        sincosf((float)l * invf, &sn, &cs);
        rtab[idx] = make_float2(cs, sn);
    }
}

// ---------------------------------------------------------------------------
// K2: f16 MFMA GEMM  C[M,N] = A[M,1024] * W[N,1024]^T
// BM x BN tile, BK=32, 4 waves in 2x2. Single-barrier double-buffered K-loop:
// per iteration: barrier (drains prefetch that had the whole previous compute
// phase in flight) -> issue DMA for next tile into the other buffer ->
// compute current. Reads of buf[cur] are complete before each wave passes the
// barrier, so overwriting buf[cur] next iteration is safe with ONE barrier.
// XOR source-swizzle keeps fragment ds_read_b128 conflict-free (2-way).
// ---------------------------------------------------------------------------
template <typename OutT, int BM, int BN>
__global__ __launch_bounds__(256) void gemm_f16_kernel(const _Float16* __restrict__ A,
                                                       const _Float16* __restrict__ W,
                                                       OutT* __restrict__ C, int N) {
    constexpr int WM = BM / 2, WN = BN / 2;
    constexpr int MT = WM / 16, NT = WN / 16;
    __shared__ _Float16 As[2][BM * 32];
    __shared__ _Float16 Bs[2][BN * 32];
    int t = threadIdx.x;
    int w = t >> 6, lane = t & 63;
    int quad = lane >> 4, col = lane & 15;
    int m0 = blockIdx.y * BM, n0 = blockIdx.x * BN;
    int mw = (w >> 1) * WM, nw = (w & 1) * WN;
    int sw = (col >> 1) & 3;  // fragment-read swizzle == (row>>1)&3 for row=…+col

    f32x4 acc[MT][NT] = {};

    auto stage = [&](int k0, int buf) {
#pragma unroll
        for (int i = 0; i < BM / 64; i++) {
            int e = t + i * 256;
            int row = e >> 2, kc = (e & 3) ^ ((row >> 1) & 3);
            __builtin_amdgcn_global_load_lds(
                (const __attribute__((address_space(1))) void*)&A[(size_t)(m0 + row) * 1024 + k0 + kc * 8],
                (__attribute__((address_space(3))) void*)&As[buf][e * 8], 16, 0, 0);
        }
#pragma unroll
        for (int i = 0; i < BN / 64; i++) {
            int e = t + i * 256;
            int row = e >> 2, kc = (e & 3) ^ ((row >> 1) & 3);
            __builtin_amdgcn_global_load_lds(
                (const __attribute__((address_space(1))) void*)&W[(size_t)(n0 + row) * 1024 + k0 + kc * 8],
                (__attribute__((address_space(3))) void*)&Bs[buf][e * 8], 16, 0, 0);
        }
    };

    stage(0, 0);
    int cur = 0;
    for (int k0 = 0; k0 < 1024; k0 += 32) {
        __syncthreads();
        if (k0 + 32 < 1024) stage(k0 + 32, cur ^ 1);
        half8 af[MT], bf[NT];
#pragma unroll
        for (int mt = 0; mt < MT; mt++)
            af[mt] = *(const half8*)&As[cur][(mw + mt * 16 + col) * 32 + ((quad ^ sw) << 3)];
#pragma unroll
        for (int nt = 0; nt < NT; nt++)
            bf[nt] = *(const half8*)&Bs[cur][(nw + nt * 16 + col) * 32 + ((quad ^ sw) << 3)];
#pragma unroll
        for (int mt = 0; mt < MT; mt++)
#pragma unroll
            for (int nt = 0; nt < NT; nt++)
                acc[mt][nt] = __builtin_amdgcn_mfma_f32_16x16x32_f16(af[mt], bf[nt], acc[mt][nt], 0, 0, 0);
        cur ^= 1;
    }

#pragma unroll
    for (int mt = 0; mt < MT; mt++)
#pragma unroll
        for (int nt = 0; nt < NT; nt++)
#pragma unroll
            for (int r = 0; r < 4; r++) {
                int row = m0 + mw + mt * 16 + quad * 4 + r;
                int cc = n0 + nw + nt * 16 + col;
                C[(size_t)row * N + cc] = (OutT)acc[mt][nt][r];
            }
}

// ---------------------------------------------------------------------------
// K3: mid kernel — fuses:
//  [0,8192)      Q/K LayerNorm + RoPE (table-based) -> f16 q_r/k_r [B,H,L,DH]
//  [8192,9216)   V extract/transpose -> f16 v_t [B*H][DH][L]
// ---------------------------------------------------------------------------
__global__ __launch_bounds__(256) void mid_kernel(const _Float16* __restrict__ qkv,
                                                  const float* __restrict__ qw,
                                                  const float* __restrict__ kw,
                                                  const float2* __restrict__ rtab,
                                                  _Float16* __restrict__ q_r,
                                                  _Float16* __restrict__ k_r,
                                                  _Float16* __restrict__ v_t) {
    __shared__ float ls[4], lq[4];
    __shared__ _Float16 T[64][72];
    int blk = blockIdx.x;
    int t = threadIdx.x;
    if (blk < 8192) {
        int r = blk >> 1;
        int which = blk & 1;  // 0 = q, 1 = k
        const _Float16* src = qkv + (size_t)r * 3072 + which * 1024;
        const float* w = which ? kw : qw;
        _Float16* dst = which ? k_r : q_r;

        float vals[4];
        float s = 0.f, sq = 0.f;
#pragma unroll
        for (int i = 0; i < 4; i++) {
            float v = (float)src[t + i * 256];
            vals[i] = v;
            s += v;
            sq += v * v;
        }
        for (int off = 32; off > 0; off >>= 1) {
            s += __shfl_xor(s, off, 64);
            sq += __shfl_xor(sq, off, 64);
        }
        int wave = t >> 6;
        if ((t & 63) == 0) { ls[wave] = s; lq[wave] = sq; }
        __syncthreads();
        float S = ls[0] + ls[1] + ls[2] + ls[3];
        float Q = lq[0] + lq[1] + lq[2] + lq[3];
        float mu = S / 1024.f;
        float rs = rsqrtf(Q / 1024.f - mu * mu + EPS);

        int l = r & (L - 1);
        int b = r >> 11;
#pragma unroll
        for (int i = 0; i < 4; i++) {
            int j = t + i * 256;
            float y = (vals[i] - mu) * rs * w[j];
            float p = __shfl_xor(y, 32, 64);  // partner element j^32 (same head)
            int dh = j & 63, hh = j >> 6;
            float2 cs = rtab[l * 32 + (dh & 31)];
            float out = (dh < 32) ? (y * cs.x - p * cs.y) : (y * cs.x + p * cs.y);
            dst[((size_t)((b * H + hh) * L + l)) * 64 + dh] = (_Float16)out;
        }
    } else {
        int vb = blk - 8192;
        int bh = vb >> 5;
        int b = bh >> 4, h = bh & 15;
        int l0 = (vb & 31) * 64;
#pragma unroll
        for (int i = 0; i < 2; i++) {
            int e = t + i * 256;
            int li = e >> 3, ch = e & 7;
            half8 hv = *(const half8*)&qkv[((size_t)(b * L + l0 + li)) * 3072 + 2048 + h * 64 + ch * 8];
            *(half8*)&T[li][ch * 8] = hv;
        }
        __syncthreads();
#pragma unroll
        for (int i = 0; i < 2; i++) {
            int e = t + i * 256;
            int d = e >> 3, ch = e & 7;
            half8 hv;
#pragma unroll
            for (int j = 0; j < 8; j++) hv[j] = T[ch * 8 + j][d];
            *(half8*)&v_t[((size_t)(bh * 64 + d)) * 2048 + l0 + ch * 8] = hv;
        }
    }
}

// ---------------------------------------------------------------------------
// K4: MFMA flash attention, segment-pruned. ctx output in f16.
// ---------------------------------------------------------------------------
__global__ __launch_bounds__(256) void attn_mfma_kernel(const _Float16* __restrict__ q_r,
                                                        const _Float16* __restrict__ k_r,
                                                        const _Float16* __restrict__ v_t,
                                                        const int* __restrict__ lo_arr,
                                                        const int* __restrict__ hi_arr,
                                                        _Float16* __restrict__ ctx) {
    __shared__ _Float16 Ks[64][72];
    __shared__ _Float16 VsT[64][72];
    __shared__ _Float16 Ps[4][16][72];
    int bh = blockIdx.y;
    int b = bh >> 4, h = bh & 15;
    int l0 = blockIdx.x * 64;
    int t = threadIdx.x;
    int w = t >> 6, lane = t & 63;
    int quad = lane >> 4, col = lane & 15;
    int rbase = l0 + w * 16;

    half8 qf0, qf1;
    {
        const _Float16* qp = q_r + ((size_t)(bh * L + rbase + col)) * 64 + quad * 8;
        qf0 = *(const half8*)qp;
        qf1 = *(const half8*)(qp + 32);
    }
    int myrow = rbase + quad * 4;
    int lo_r[4], hi_r[4];
#pragma unroll
    for (int r = 0; r < 4; r++) {
        lo_r[r] = lo_arr[b * L + myrow + r];
        hi_r[r] = hi_arr[b * L + myrow + r];
    }

    f32x4 o[4] = {{0.f, 0.f, 0.f, 0.f}, {0.f, 0.f, 0.f, 0.f},
                  {0.f, 0.f, 0.f, 0.f}, {0.f, 0.f, 0.f, 0.f}};
    float m_run[4], l_run[4];
#pragma unroll
    for (int r = 0; r < 4; r++) { m_run[r] = -1e30f; l_run[r] = 0.f; }

    int blo = lo_arr[b * L + l0] & ~63;
    int bhi = hi_arr[b * L + l0 + 63];

    for (int m0 = blo; m0 < bhi; m0 += 64) {
#pragma unroll
        for (int i = 0; i < 2; i++) {
            int e = t + i * 256;
            int row = e >> 3, ch = e & 7;
            *(uint4*)&Ks[row][ch * 8] =
                *(const uint4*)&k_r[((size_t)(bh * L + m0 + row)) * 64 + ch * 8];
            *(uint4*)&VsT[row][ch * 8] =
                *(const uint4*)&v_t[((size_t)(bh * 64 + row)) * 2048 + m0 + ch * 8];
        }
        __syncthreads();

        f32x4 s[4] = {{0.f, 0.f, 0.f, 0.f}, {0.f, 0.f, 0.f, 0.f},
                      {0.f, 0.f, 0.f, 0.f}, {0.f, 0.f, 0.f, 0.f}};
#pragma unroll
        for (int nt = 0; nt < 4; nt++) {
            const _Float16* kp = &Ks[nt * 16 + col][quad * 8];
            half8 kf0 = *(const half8*)kp;
            half8 kf1 = *(const half8*)(kp + 32);
            s[nt] = __builtin_amdgcn_mfma_f32_16x16x32_f16(qf0, kf0, s[nt], 0, 0, 0);
            s[nt] = __builtin_amdgcn_mfma_f32_16x16x32_f16(qf1, kf1, s[nt], 0, 0, 0);
        }

        float p[4][4];
#pragma unroll
        for (int nt = 0; nt < 4; nt++) {
            int key = m0 + nt * 16 + col;
#pragma unroll
            for (int r = 0; r < 4; r++) {
                float v = s[nt][r] * 0.125f;
                p[nt][r] = (key >= lo_r[r] && key < hi_r[r]) ? v : -INFINITY;
            }
        }

        float corr[4];
#pragma unroll
        for (int r = 0; r < 4; r++) {
            float rm = fmaxf(fmaxf(p[0][r], p[1][r]), fmaxf(p[2][r], p[3][r]));
#pragma unroll
            for (int off = 1; off < 16; off <<= 1) rm = fmaxf(rm, __shfl_xor(rm, off, 64));
            float nm = fmaxf(m_run[r], rm);
            corr[r] = __expf(m_run[r] - nm);
            m_run[r] = nm;
            float rs = 0.f;
#pragma unroll
            for (int nt = 0; nt < 4; nt++) {
                float e = __expf(p[nt][r] - nm);
                p[nt][r] = e;
                rs += e;
            }
#pragma unroll
            for (int off = 1; off < 16; off <<= 1) rs += __shfl_xor(rs, off, 64);
            l_run[r] = l_run[r] * corr[r] + rs;
        }

#pragma unroll
        for (int nt = 0; nt < 4; nt++)
#pragma unroll
            for (int r = 0; r < 4; r++) {
                o[nt][r] *= corr[r];
                Ps[w][quad * 4 + r][nt * 16 + col] = (_Float16)p[nt][r];
            }
        __syncthreads();

        half8 pf0 = *(const half8*)&Ps[w][col][quad * 8];
        half8 pf1 = *(const half8*)&Ps[w][col][32 + quad * 8];
#pragma unroll
        for (int nt = 0; nt < 4; nt++) {
            const _Float16* vp = &VsT[nt * 16 + col][quad * 8];
            half8 vf0 = *(const half8*)vp;
            half8 vf1 = *(const half8*)(vp + 32);
            o[nt] = __builtin_amdgcn_mfma_f32_16x16x32_f16(pf0, vf0, o[nt], 0, 0, 0);
            o[nt] = __builtin_amdgcn_mfma_f32_16x16x32_f16(pf1, vf1, o[nt], 0, 0, 0);
        }
        __syncthreads();
    }

#pragma unroll
    for (int nt = 0; nt < 4; nt++)
#pragma unroll
        for (int r = 0; r < 4; r++) {
            int row = myrow + r;
            ctx[((size_t)(b * L + row)) * 1024 + h * 64 + nt * 16 + col] =
                (_Float16)(o[nt][r] / l_run[r]);
        }
}

// ---------------------------------------------------------------------------
// launch
// ---------------------------------------------------------------------------
extern "C" void kernel_launch(void* const* d_in, const int* in_sizes, int n_in,
                              void* d_out, int out_size, void* d_ws, size_t ws_size,
                              hipStream_t stream) {
    const float* x      = (const float*)d_in[0];
    const int*   seq_id = (const int*)d_in[1];
    const float* ln1_w  = (const float*)d_in[2];
    const float* ln1_b  = (const float*)d_in[3];
    const float* w_qkv  = (const float*)d_in[4];
    const float* q_ln_w = (const float*)d_in[5];
    const float* k_ln_w = (const float*)d_in[6];
    const float* out_w  = (const float*)d_in[7];
    float* out = (float*)d_out;

    char* ws = (char*)d_ws;
    int*      lo     = (int*)(ws);                        // 16 KB
    int*      hi     = (int*)(ws + (64 << 10));           // 16 KB
    float2*   rtab   = (float2*)(ws + (128 << 10));       // [2048][32] f32x2, 512 KB
    _Float16* h16    = (_Float16*)(ws + (1ull << 20));    // [4096,1024] 8 MB
    _Float16* wqkv16 = (_Float16*)(ws + (10ull << 20));   // [3072,1024] 6 MB
    _Float16* outw16 = (_Float16*)(ws + (17ull << 20));   // [1024,1024] 2 MB
    _Float16* qkv16  = (_Float16*)(ws + (20ull << 20));   // [4096,3072] 24 MB
    _Float16* q_r    = (_Float16*)(ws + (45ull << 20));   // [B,H,L,DH] 8 MB
    _Float16* k_r    = (_Float16*)(ws + (54ull << 20));   // 8 MB
    _Float16* v_t    = (_Float16*)(ws + (63ull << 20));   // [B,H,DH,L] 8 MB
    _Float16* ctx16  = (_Float16*)(ws + (72ull << 20));   // [4096,1024] 8 MB

    prep_kernel<<<dim3(6416), dim3(256), 0, stream>>>(
        x, ln1_w, ln1_b, h16, w_qkv, wqkv16, out_w, outw16, seq_id, lo, hi, rtab);
    gemm_f16_kernel<_Float16, 128, 128><<<dim3(3072 / 128, NROW / 128), dim3(256), 0, stream>>>(
        h16, wqkv16, qkv16, 3072);
    mid_kernel<<<dim3(9216), dim3(256), 0, stream>>>(qkv16, q_ln_w, k_ln_w, rtab, q_r, k_r, v_t);
    attn_mfma_kernel<<<dim3(L / 64, B * H), dim3(256), 0, stream>>>(q_r, k_r, v_t, lo, hi, ctx16);
    gemm_f16_kernel<float, 128, 64><<<dim3(1024 / 64, NROW / 128), dim3(256), 0, stream>>>(
        ctx16, outw16, out, 1024);

    (void)in_sizes; (void)n_in; (void)out_size; (void)ws_size;
}

// Round 8
// 197.295 us; speedup vs baseline: 1.0254x; 1.0071x over previous
//
#include <hip/hip_runtime.h>
#include <hip/hip_bf16.h>
#include <math.h>

#define D 1024
#define H 16
#define DH 64
#define L 2048
#define B 2
#define NROW (B * L)  // 4096
#define EPS 1e-5f

typedef _Float16 half8 __attribute__((ext_vector_type(8)));
typedef _Float16 half4v __attribute__((ext_vector_type(4)));
typedef float f32x4 __attribute__((ext_vector_type(4)));

// ---------------------------------------------------------------------------
// K1: prep kernel — fuses 4 independent preprocessing jobs, block-ranged:
//  [0,4096)      LN1 (stats+apply) -> h16
//  [4096,6144)   f32->f16 weight convert (w_qkv then out_w)
//  [6144,6160)   segment bounds from sorted seq_id
//  [6160,6416)   rope cos/sin table [L][32] (float2)
// ---------------------------------------------------------------------------
__global__ __launch_bounds__(256) void prep_kernel(const float* __restrict__ x,
                                                   const float* __restrict__ lw,
                                                   const float* __restrict__ lb,
                                                   _Float16* __restrict__ h16,
                                                   const float* __restrict__ wqkv,
                                                   _Float16* __restrict__ wqkv16,
                                                   const float* __restrict__ outw,
                                                   _Float16* __restrict__ outw16,
                                                   const int* __restrict__ seq_id,
                                                   int* __restrict__ lo,
                                                   int* __restrict__ hi,
                                                   float2* __restrict__ rtab) {
    int blk = blockIdx.x;
    int t = threadIdx.x;
    if (blk < 4096) {
        // ---- LN1 row ----
        int r = blk;
        const float* xr = x + (size_t)r * D;
        float4 v = *(const float4*)&xr[t * 4];
        float s = v.x + v.y + v.z + v.w;
        float sq = v.x * v.x + v.y * v.y + v.z * v.z + v.w * v.w;
        for (int off = 32; off > 0; off >>= 1) {
            s += __shfl_xor(s, off, 64);
            sq += __shfl_xor(sq, off, 64);
        }
        __shared__ float ls[4], lq[4];
        int wave = t >> 6;
        if ((t & 63) == 0) { ls[wave] = s; lq[wave] = sq; }
        __syncthreads();
        float S = ls[0] + ls[1] + ls[2] + ls[3];
        float Q = lq[0] + lq[1] + lq[2] + lq[3];
        float mu = S / (float)D;
        float rs = rsqrtf(Q / (float)D - mu * mu + EPS);
        float4 w4 = *(const float4*)&lw[t * 4];
        float4 b4 = *(const float4*)&lb[t * 4];
        half4v o = {(_Float16)((v.x - mu) * rs * w4.x + b4.x),
                    (_Float16)((v.y - mu) * rs * w4.y + b4.y),
                    (_Float16)((v.z - mu) * rs * w4.z + b4.z),
                    (_Float16)((v.w - mu) * rs * w4.w + b4.w)};
        *(half4v*)&h16[(size_t)r * D + t * 4] = o;
    } else if (blk < 6144) {
        // ---- weight convert ----
        int base = blk - 4096;
        const float* src;
        _Float16* dst;
        if (base < 1536) { src = wqkv; dst = wqkv16; }
        else             { src = outw; dst = outw16; base -= 1536; }
        int i = (base * 256 + t) * 8;
        float4 a = *(const float4*)&src[i];
        float4 b = *(const float4*)&src[i + 4];
        half8 h = {(_Float16)a.x, (_Float16)a.y, (_Float16)a.z, (_Float16)a.w,
                   (_Float16)b.x, (_Float16)b.y, (_Float16)b.z, (_Float16)b.w};
        *(half8*)&dst[i] = h;
    } else if (blk < 6160) {
        // ---- segment bounds ----
        int idx = (blk - 6144) * 256 + t;
        int b = idx / L, l = idx - b * L;
        const int* row = seq_id + (size_t)b * L;
        int v = row[l];
        int a = 0, c = L;
        while (a < c) { int m = (a + c) >> 1; if (row[m] < v) a = m + 1; else c = m; }
        lo[idx] = a;
        a = 0; c = L;
        while (a < c) { int m = (a + c) >> 1; if (row[m] <= v) a = m + 1; else c = m; }
        hi[idx] = a;
    } else {
        // ---- rope table: rtab[l*32+fi] = (cos, sin) of l * 10000^(-fi/32) ----
        int idx = (blk - 6160) * 256 + t;  // 0..65535
        int l = idx >> 5, fi = idx & 31;
        float invf = expf(-(float)fi * 0.28782313662425572f);  // ln(10000)/32
        float sn, cs;
        sincosf((float)l * invf, &sn, &cs);
        rtab[idx] = make_float2(cs, sn);
    }
}

// ---------------------------------------------------------------------------
// K2: f16 MFMA GEMM  C[M,N] = A[M,1024] * W[N,1024]^T
// BM x BN tile, BK=32, 4 waves in 2x2. Single-barrier double-buffered K-loop
// (prefetch gets the whole previous compute phase in flight before the
// compiler's vmcnt(0)-before-barrier drains it — deeper pipelining is
// defeated by that drain, per m131-m141, so we stop at depth 2).
// XOR source-swizzle keeps fragment ds_read_b128 conflict-free (2-way).
// ---------------------------------------------------------------------------
template <typename OutT, int BM, int BN>
__global__ __launch_bounds__(256) void gemm_f16_kernel(const _Float16* __restrict__ A,
                                                       const _Float16* __restrict__ W,
                                                       OutT* __restrict__ C, int N) {
    constexpr int WM = BM / 2, WN = BN / 2;
    constexpr int MT = WM / 16, NT = WN / 16;
    __shared__ _Float16 As[2][BM * 32];
    __shared__ _Float16 Bs[2][BN * 32];
    int t = threadIdx.x;
    int w = t >> 6, lane = t & 63;
    int quad = lane >> 4, col = lane & 15;
    int m0 = blockIdx.y * BM, n0 = blockIdx.x * BN;
    int mw = (w >> 1) * WM, nw = (w & 1) * WN;
    int sw = (col >> 1) & 3;  // fragment-read swizzle == (row>>1)&3 for row=…+col

    f32x4 acc[MT][NT] = {};

    auto stage = [&](int k0, int buf) {
#pragma unroll
        for (int i = 0; i < BM / 64; i++) {
            int e = t + i * 256;
            int row = e >> 2, kc = (e & 3) ^ ((row >> 1) & 3);
            __builtin_amdgcn_global_load_lds(
                (const __attribute__((address_space(1))) void*)&A[(size_t)(m0 + row) * 1024 + k0 + kc * 8],
                (__attribute__((address_space(3))) void*)&As[buf][e * 8], 16, 0, 0);
        }
#pragma unroll
        for (int i = 0; i < BN / 64; i++) {
            int e = t + i * 256;
            int row = e >> 2, kc = (e & 3) ^ ((row >> 1) & 3);
            __builtin_amdgcn_global_load_lds(
                (const __attribute__((address_space(1))) void*)&W[(size_t)(n0 + row) * 1024 + k0 + kc * 8],
                (__attribute__((address_space(3))) void*)&Bs[buf][e * 8], 16, 0, 0);
        }
    };

    stage(0, 0);
    int cur = 0;
    for (int k0 = 0; k0 < 1024; k0 += 32) {
        __syncthreads();
        if (k0 + 32 < 1024) stage(k0 + 32, cur ^ 1);
        half8 af[MT], bf[NT];
#pragma unroll
        for (int mt = 0; mt < MT; mt++)
            af[mt] = *(const half8*)&As[cur][(mw + mt * 16 + col) * 32 + ((quad ^ sw) << 3)];
#pragma unroll
        for (int nt = 0; nt < NT; nt++)
            bf[nt] = *(const half8*)&Bs[cur][(nw + nt * 16 + col) * 32 + ((quad ^ sw) << 3)];
#pragma unroll
        for (int mt = 0; mt < MT; mt++)
#pragma unroll
            for (int nt = 0; nt < NT; nt++)
                acc[mt][nt] = __builtin_amdgcn_mfma_f32_16x16x32_f16(af[mt], bf[nt], acc[mt][nt], 0, 0, 0);
        cur ^= 1;
    }

#pragma unroll
    for (int mt = 0; mt < MT; mt++)
#pragma unroll
        for (int nt = 0; nt < NT; nt++)
#pragma unroll
            for (int r = 0; r < 4; r++) {
                int row = m0 + mw + mt * 16 + quad * 4 + r;
                int cc = n0 + nw + nt * 16 + col;
                C[(size_t)row * N + cc] = (OutT)acc[mt][nt][r];
            }
}

// ---------------------------------------------------------------------------
// K3: mid kernel — fuses:
//  [0,8192)      Q/K LayerNorm + RoPE (table-based) -> f16 q_r/k_r [B,H,L,DH]
//  [8192,9216)   V extract/transpose -> f16 v_t [B*H][DH][L]
// ---------------------------------------------------------------------------
__global__ __launch_bounds__(256) void mid_kernel(const _Float16* __restrict__ qkv,
                                                  const float* __restrict__ qw,
                                                  const float* __restrict__ kw,
                                                  const float2* __restrict__ rtab,
                                                  _Float16* __restrict__ q_r,
                                                  _Float16* __restrict__ k_r,
                                                  _Float16* __restrict__ v_t) {
    __shared__ float ls[4], lq[4];
    __shared__ _Float16 T[64][72];
    int blk = blockIdx.x;
    int t = threadIdx.x;
    if (blk < 8192) {
        int r = blk >> 1;
        int which = blk & 1;  // 0 = q, 1 = k
        const _Float16* src = qkv + (size_t)r * 3072 + which * 1024;
        const float* w = which ? kw : qw;
        _Float16* dst = which ? k_r : q_r;

        float vals[4];
        float s = 0.f, sq = 0.f;
#pragma unroll
        for (int i = 0; i < 4; i++) {
            float v = (float)src[t + i * 256];
            vals[i] = v;
            s += v;
            sq += v * v;
        }
        for (int off = 32; off > 0; off >>= 1) {
            s += __shfl_xor(s, off, 64);
            sq += __shfl_xor(sq, off, 64);
        }
        int wave = t >> 6;
        if ((t & 63) == 0) { ls[wave] = s; lq[wave] = sq; }
        __syncthreads();
        float S = ls[0] + ls[1] + ls[2] + ls[3];
        float Q = lq[0] + lq[1] + lq[2] + lq[3];
        float mu = S / 1024.f;
        float rs = rsqrtf(Q / 1024.f - mu * mu + EPS);

        int l = r & (L - 1);
        int b = r >> 11;
#pragma unroll
        for (int i = 0; i < 4; i++) {
            int j = t + i * 256;
            float y = (vals[i] - mu) * rs * w[j];
            float p = __shfl_xor(y, 32, 64);  // partner element j^32 (same head)
            int dh = j & 63, hh = j >> 6;
            float2 cs = rtab[l * 32 + (dh & 31)];
            float out = (dh < 32) ? (y * cs.x - p * cs.y) : (y * cs.x + p * cs.y);
            dst[((size_t)((b * H + hh) * L + l)) * 64 + dh] = (_Float16)out;
        }
    } else {
        int vb = blk - 8192;
        int bh = vb >> 5;
        int b = bh >> 4, h = bh & 15;
        int l0 = (vb & 31) * 64;
#pragma unroll
        for (int i = 0; i < 2; i++) {
            int e = t + i * 256;
            int li = e >> 3, ch = e & 7;
            half8 hv = *(const half8*)&qkv[((size_t)(b * L + l0 + li)) * 3072 + 2048 + h * 64 + ch * 8];
            *(half8*)&T[li][ch * 8] = hv;
        }
        __syncthreads();
#pragma unroll
        for (int i = 0; i < 2; i++) {
            int e = t + i * 256;
            int d = e >> 3, ch = e & 7;
            half8 hv;
#pragma unroll
            for (int j = 0; j < 8; j++) hv[j] = T[ch * 8 + j][d];
            *(half8*)&v_t[((size_t)(bh * 64 + d)) * 2048 + l0 + ch * 8] = hv;
        }
    }
}

// ---------------------------------------------------------------------------
// K4: MFMA flash attention, segment-pruned. ctx output in f16.
// 2 barriers per key-tile: Ps is wave-private LDS (write->read ordered by
// lgkmcnt within the wave), so no barrier is needed around it; the loop-end
// barrier alone protects Ks/VsT reuse across tiles.
// Softmax in base-2: S*scale*log2(e) once, exp2 everywhere.
// ---------------------------------------------------------------------------
__global__ __launch_bounds__(256) void attn_mfma_kernel(const _Float16* __restrict__ q_r,
                                                        const _Float16* __restrict__ k_r,
                                                        const _Float16* __restrict__ v_t,
                                                        const int* __restrict__ lo_arr,
                                                        const int* __restrict__ hi_arr,
                                                        _Float16* __restrict__ ctx) {
    __shared__ _Float16 Ks[64][72];
    __shared__ _Float16 VsT[64][72];
    __shared__ _Float16 Ps[4][16][72];
    int bh = blockIdx.y;
    int b = bh >> 4, h = bh & 15;
    int l0 = blockIdx.x * 64;
    int t = threadIdx.x;
    int w = t >> 6, lane = t & 63;
    int quad = lane >> 4, col = lane & 15;
    int rbase = l0 + w * 16;

    half8 qf0, qf1;
    {
        const _Float16* qp = q_r + ((size_t)(bh * L + rbase + col)) * 64 + quad * 8;
        qf0 = *(const half8*)qp;
        qf1 = *(const half8*)(qp + 32);
    }
    int myrow = rbase + quad * 4;
    int lo_r[4], hi_r[4];
#pragma unroll
    for (int r = 0; r < 4; r++) {
        lo_r[r] = lo_arr[b * L + myrow + r];
        hi_r[r] = hi_arr[b * L + myrow + r];
    }

    f32x4 o[4] = {{0.f, 0.f, 0.f, 0.f}, {0.f, 0.f, 0.f, 0.f},
                  {0.f, 0.f, 0.f, 0.f}, {0.f, 0.f, 0.f, 0.f}};
    float m_run[4], l_run[4];
#pragma unroll
    for (int r = 0; r < 4; r++) { m_run[r] = -1e30f; l_run[r] = 0.f; }

    int blo = lo_arr[b * L + l0] & ~63;
    int bhi = hi_arr[b * L + l0 + 63];
    const float SCL = 0.125f * 1.4426950408889634f;  // (1/sqrt(DH)) * log2(e)

    for (int m0 = blo; m0 < bhi; m0 += 64) {
#pragma unroll
        for (int i = 0; i < 2; i++) {
            int e = t + i * 256;
            int row = e >> 3, ch = e & 7;
            *(uint4*)&Ks[row][ch * 8] =
                *(const uint4*)&k_r[((size_t)(bh * L + m0 + row)) * 64 + ch * 8];
            *(uint4*)&VsT[row][ch * 8] =
                *(const uint4*)&v_t[((size_t)(bh * 64 + row)) * 2048 + m0 + ch * 8];
        }
        __syncthreads();

        f32x4 s[4] = {{0.f, 0.f, 0.f, 0.f}, {0.f, 0.f, 0.f, 0.f},
                      {0.f, 0.f, 0.f, 0.f}, {0.f, 0.f, 0.f, 0.f}};
#pragma unroll
        for (int nt = 0; nt < 4; nt++) {
            const _Float16* kp = &Ks[nt * 16 + col][quad * 8];
            half8 kf0 = *(const half8*)kp;
            half8 kf1 = *(const half8*)(kp + 32);
            s[nt] = __builtin_amdgcn_mfma_f32_16x16x32_f16(qf0, kf0, s[nt], 0, 0, 0);
            s[nt] = __builtin_amdgcn_mfma_f32_16x16x32_f16(qf1, kf1, s[nt], 0, 0, 0);
        }

        // p = log2-domain score; masked = -inf
        float p[4][4];
#pragma unroll
        for (int nt = 0; nt < 4; nt++) {
            int key = m0 + nt * 16 + col;
#pragma unroll
            for (int r = 0; r < 4; r++) {
                float v = s[nt][r] * SCL;
                p[nt][r] = (key >= lo_r[r] && key < hi_r[r]) ? v : -INFINITY;
            }
        }

        float corr[4];
#pragma unroll
        for (int r = 0; r < 4; r++) {
            float rm = fmaxf(fmaxf(p[0][r], p[1][r]), fmaxf(p[2][r], p[3][r]));
#pragma unroll
            for (int off = 1; off < 16; off <<= 1) rm = fmaxf(rm, __shfl_xor(rm, off, 64));
            float nm = fmaxf(m_run[r], rm);
            corr[r] = exp2f(m_run[r] - nm);
            m_run[r] = nm;
            float rs = 0.f;
#pragma unroll
            for (int nt = 0; nt < 4; nt++) {
                float e = exp2f(p[nt][r] - nm);
                p[nt][r] = e;
                rs += e;
            }
#pragma unroll
            for (int off = 1; off < 16; off <<= 1) rs += __shfl_xor(rs, off, 64);
            l_run[r] = l_run[r] * corr[r] + rs;
        }

        // write P (C-layout) to wave-private LDS; no barrier needed (lgkmcnt
        // orders intra-wave ds_write->ds_read; no other wave touches Ps[w])
#pragma unroll
        for (int nt = 0; nt < 4; nt++)
#pragma unroll
            for (int r = 0; r < 4; r++) {
                o[nt][r] *= corr[r];
                Ps[w][quad * 4 + r][nt * 16 + col] = (_Float16)p[nt][r];
            }

        half8 pf0 = *(const half8*)&Ps[w][col][quad * 8];
        half8 pf1 = *(const half8*)&Ps[w][col][32 + quad * 8];
#pragma unroll
        for (int nt = 0; nt < 4; nt++) {
            const _Float16* vp = &VsT[nt * 16 + col][quad * 8];
            half8 vf0 = *(const half8*)vp;
            half8 vf1 = *(const half8*)(vp + 32);
            o[nt] = __builtin_amdgcn_mfma_f32_16x16x32_f16(pf0, vf0, o[nt], 0, 0, 0);
            o[nt] = __builtin_amdgcn_mfma_f32_16x16x32_f16(pf1, vf1, o[nt], 0, 0, 0);
        }
        __syncthreads();
    }

#pragma unroll
    for (int nt = 0; nt < 4; nt++)
#pragma unroll
        for (int r = 0; r < 4; r++) {
            int row = myrow + r;
            ctx[((size_t)(b * L + row)) * 1024 + h * 64 + nt * 16 + col] =
                (_Float16)(o[nt][r] / l_run[r]);
        }
}

// ---------------------------------------------------------------------------
// launch
// ---------------------------------------------------------------------------
extern "C" void kernel_launch(void* const* d_in, const int* in_sizes, int n_in,
                              void* d_out, int out_size, void* d_ws, size_t ws_size,
                              hipStream_t stream) {
    const float* x      = (const float*)d_in[0];
    const int*   seq_id = (const int*)d_in[1];
    const float* ln1_w  = (const float*)d_in[2];
    const float* ln1_b  = (const float*)d_in[3];
    const float* w_qkv  = (const float*)d_in[4];
    const float* q_ln_w = (const float*)d_in[5];
    const float* k_ln_w = (const float*)d_in[6];
    const float* out_w  = (const float*)d_in[7];
    float* out = (float*)d_out;

    char* ws = (char*)d_ws;
    int*      lo     = (int*)(ws);                        // 16 KB
    int*      hi     = (int*)(ws + (64 << 10));           // 16 KB
    float2*   rtab   = (float2*)(ws + (128 << 10));       // [2048][32] f32x2, 512 KB
    _Float16* h16    = (_Float16*)(ws + (1ull << 20));    // [4096,1024] 8 MB
    _Float16* wqkv16 = (_Float16*)(ws + (10ull << 20));   // [3072,1024] 6 MB
    _Float16* outw16 = (_Float16*)(ws + (17ull << 20));   // [1024,1024] 2 MB
    _Float16* qkv16  = (_Float16*)(ws + (20ull << 20));   // [4096,3072] 24 MB
    _Float16* q_r    = (_Float16*)(ws + (45ull << 20));   // [B,H,L,DH] 8 MB
    _Float16* k_r    = (_Float16*)(ws + (54ull << 20));   // 8 MB
    _Float16* v_t    = (_Float16*)(ws + (63ull << 20));   // [B,H,DH,L] 8 MB
    _Float16* ctx16  = (_Float16*)(ws + (72ull << 20));   // [4096,1024] 8 MB

    prep_kernel<<<dim3(6416), dim3(256), 0, stream>>>(
        x, ln1_w, ln1_b, h16, w_qkv, wqkv16, out_w, outw16, seq_id, lo, hi, rtab);
    gemm_f16_kernel<_Float16, 128, 128><<<dim3(3072 / 128, NROW / 128), dim3(256), 0, stream>>>(
        h16, wqkv16, qkv16, 3072);
    mid_kernel<<<dim3(9216), dim3(256), 0, stream>>>(qkv16, q_ln_w, k_ln_w, rtab, q_r, k_r, v_t);
    attn_mfma_kernel<<<dim3(L / 64, B * H), dim3(256), 0, stream>>>(q_r, k_r, v_t, lo, hi, ctx16);
    gemm_f16_kernel<float, 128, 64><<<dim3(1024 / 64, NROW / 128), dim3(256), 0, stream>>>(
        ctx16, outw16, out, 1024);

    (void)in_sizes; (void)n_in; (void)out_size; (void)ws_size;
}